// Round 8
// baseline (419.998 us; speedup 1.0000x reference)
//
#include <hip/hip_runtime.h>
#include <math.h>

#define NF 1433
#define NH 16
#define NC 7
#define NCH 45          // ceil(1433/32), odd
#define NBKT_MAX 512    // supports n <= 131072 (bucket = dst>>8)
#define SC2 3072        // LDS-sortable sub-chunk
#define CB 256          // CSR blocks in fused kernel
#define GB 768          // gemm blocks in fused kernel

typedef __attribute__((ext_vector_type(8))) short bf16x8;
typedef __attribute__((ext_vector_type(4))) float f32x4;

__device__ __forceinline__ unsigned short f2bf(float f) {
  unsigned int u = __float_as_uint(f);
  unsigned int r = (u + 0x7FFFu + ((u >> 16) & 1u)) >> 16;  // RNE
  return (unsigned short)r;
}
__device__ __forceinline__ unsigned int packbf(float lo, float hi) {
  return (unsigned int)f2bf(lo) | ((unsigned int)f2bf(hi) << 16);
}
// a[i] += 8 bf16 (packed uint4), plain
__device__ __forceinline__ void acc8(float* a, uint4 r) {
  a[0] += __uint_as_float(r.x << 16); a[1] += __uint_as_float(r.x & 0xffff0000u);
  a[2] += __uint_as_float(r.y << 16); a[3] += __uint_as_float(r.y & 0xffff0000u);
  a[4] += __uint_as_float(r.z << 16); a[5] += __uint_as_float(r.z & 0xffff0000u);
  a[6] += __uint_as_float(r.w << 16); a[7] += __uint_as_float(r.w & 0xffff0000u);
}
// a[i] += c * bf16[i]  (fma, for unscaled hs1 gathers)
__device__ __forceinline__ void acc8f(float* a, uint4 r, float c) {
  a[0] = fmaf(__uint_as_float(r.x << 16), c, a[0]);
  a[1] = fmaf(__uint_as_float(r.x & 0xffff0000u), c, a[1]);
  a[2] = fmaf(__uint_as_float(r.y << 16), c, a[2]);
  a[3] = fmaf(__uint_as_float(r.y & 0xffff0000u), c, a[3]);
  a[4] = fmaf(__uint_as_float(r.z << 16), c, a[4]);
  a[5] = fmaf(__uint_as_float(r.z & 0xffff0000u), c, a[5]);
  a[6] = fmaf(__uint_as_float(r.w << 16), c, a[6]);
  a[7] = fmaf(__uint_as_float(r.w & 0xffff0000u), c, a[7]);
}

// partial barrier over the CB CSR blocks. Release flushes writer-XCD L2;
// acquire invalidates reader L1/L2 (cross-XCD visibility, G16-safe).
__device__ __forceinline__ void gbar(int* bar, int idx, int target) {
  __syncthreads();
  if (threadIdx.x == 0) {
    __threadfence();
    __hip_atomic_fetch_add(&bar[idx], 1, __ATOMIC_RELEASE, __HIP_MEMORY_SCOPE_AGENT);
    while (__hip_atomic_load(&bar[idx], __ATOMIC_ACQUIRE, __HIP_MEMORY_SCOPE_AGENT) < target)
      __builtin_amdgcn_s_sleep(2);
  }
  __syncthreads();
}

// ---------------- prep: pack W1 fragments + zero counters ----------------
// Wb[(c*64+lane)*8+i] = bf16(W1[k][col]), k = c*32+(lane>>4)*8+i, col = lane&15
__global__ void k_prep(const float* __restrict__ W1, short* __restrict__ Wb,
                       int* __restrict__ bcnt, int* __restrict__ bres,
                       int* __restrict__ bar) {
  int t = blockIdx.x * blockDim.x + threadIdx.x;
  if (t < 16 * NBKT_MAX) { bcnt[t] = 0; bres[t] = 0; }
  if (t < 16) bar[t] = 0;
  if (t >= NCH * 64 * 8) return;
  int i = t & 7, l = (t >> 3) & 63, c = t >> 9;
  int g = l >> 4, col = l & 15;
  int k = c * 32 + g * 8 + i;
  float v = (k < NF) ? W1[(size_t)k * NH + col] : 0.f;
  Wb[t] = (short)f2bf(v);
}

// ---------------- fused: CSR build (blocks 0..CB-1) || GEMM1 (rest) --------
__global__ __launch_bounds__(256, 4) void k_fused(
    const float* __restrict__ x, const short* __restrict__ Wb,
    const int* __restrict__ ei, int* __restrict__ bcnt, int* __restrict__ bres,
    int* __restrict__ bar, int* __restrict__ ebuf, int* __restrict__ off,
    int* __restrict__ srcs, float* __restrict__ dis,
    unsigned short* __restrict__ hs1, int n, int E, int nbkt) {
  __shared__ int s_gbase[NBKT_MAX];
  __shared__ int s_gcnt[NBKT_MAX];
  __shared__ int s_h[NBKT_MAX];
  __shared__ int s_lo[NBKT_MAX];
  __shared__ int s_lb[NBKT_MAX];
  __shared__ int s_sc[256];
  __shared__ int s_val[SC2];
  __shared__ unsigned short s_bkt[SC2];

  int blk = blockIdx.x, t = threadIdx.x;

  if (blk < CB) {
    // ================= CSR path =================
    const int* src = ei;
    const int* dst = ei + E;
    int perB = (E + CB - 1) / CB;
    int r0 = blk * perB, r1 = min(E, r0 + perB);

    // --- A1: histogram own region, flush to line-padded global counters
    for (int i = t; i < NBKT_MAX; i += 256) s_h[i] = 0;
    __syncthreads();
    for (int e = r0 + t; e < r1; e += 256)
      atomicAdd(&s_h[((unsigned)dst[e]) >> 8], 1);
    __syncthreads();
    for (int i = t; i < nbkt; i += 256)
      if (s_h[i]) atomicAdd(&bcnt[i * 16], s_h[i]);
    gbar(bar, 0, CB);

    // --- A2 (redundant per block): scan bcnt -> s_gbase/s_gcnt in LDS
    {
      int base = 0;
#pragma unroll
      for (int j = 0; j < 2; ++j) {
        int idx = j * 256 + t;
        int v = (idx < nbkt) ? bcnt[idx * 16] : 0;
        s_gcnt[idx] = v;
        s_sc[t] = v;
        __syncthreads();
        for (int o = 1; o < 256; o <<= 1) {
          int u = (t >= o) ? s_sc[t - o] : 0;
          __syncthreads();
          s_sc[t] += u;
          __syncthreads();
        }
        s_gbase[idx] = base + s_sc[t] - v;
        int tot = s_sc[255];
        __syncthreads();
        base += tot;
      }
    }

    // --- A3: radix-partition own region into ebuf (sub-chunks sorted in LDS)
    for (int c0 = r0; c0 < r1; c0 += SC2) {
      int c1 = min(r1, c0 + SC2);
      int csize = c1 - c0;
      for (int i = t; i < NBKT_MAX; i += 256) s_h[i] = 0;
      __syncthreads();
      for (int e = c0 + t; e < c1; e += 256)
        atomicAdd(&s_h[((unsigned)dst[e]) >> 8], 1);
      __syncthreads();
      int b2 = 0;
#pragma unroll
      for (int j = 0; j < 2; ++j) {
        int idx = j * 256 + t;
        int v = s_h[idx];
        s_sc[t] = v;
        __syncthreads();
        for (int o = 1; o < 256; o <<= 1) {
          int u = (t >= o) ? s_sc[t - o] : 0;
          __syncthreads();
          s_sc[t] += u;
          __syncthreads();
        }
        s_lo[idx] = b2 + s_sc[t] - v;
        int tot = s_sc[255];
        __syncthreads();
        b2 += tot;
      }
      for (int i = t; i < nbkt; i += 256) {
        int cc = s_h[i];
        s_lb[i] = cc ? s_gbase[i] + atomicAdd(&bres[i * 16], cc) : 0;
        s_h[i] = 0;  // reuse as cursor
      }
      __syncthreads();
      for (int e = c0 + t; e < c1; e += 256) {
        unsigned d = (unsigned)dst[e];
        int bk = d >> 8;
        int p = s_lo[bk] + atomicAdd(&s_h[bk], 1);
        s_val[p] = (int)(((d & 255u) << 24) | (unsigned)src[e]);
        s_bkt[p] = (unsigned short)bk;
      }
      __syncthreads();
      for (int i = t; i < csize; i += 256) {
        int bk = s_bkt[i];
        ebuf[s_lb[bk] + (i - s_lo[bk])] = s_val[i];
      }
      __syncthreads();
    }
    gbar(bar, 1, CB);

    // --- B: per-bucket local CSR (off, srcs, dis) from ebuf
    for (int b = blk; b < nbkt; b += CB) {
      int eb = s_gbase[b], ee = eb + s_gcnt[b];
      s_h[t] = 0;
      __syncthreads();
      for (int i = eb + t; i < ee; i += 256)
        atomicAdd(&s_h[((unsigned)ebuf[i]) >> 24], 1);
      __syncthreads();
      int deg = s_h[t];
      s_sc[t] = deg;
      __syncthreads();
      for (int o = 1; o < 256; o <<= 1) {
        int u = (t >= o) ? s_sc[t - o] : 0;
        __syncthreads();
        s_sc[t] += u;
        __syncthreads();
      }
      int excl = s_sc[t] - deg;
      int node = (b << 8) + t;
      if (node < n) {
        off[node] = eb + excl;
        dis[node] = rsqrtf((float)deg + 1.0f);
      }
      s_h[t] = eb + excl;  // fill cursor
      __syncthreads();
      for (int i = eb + t; i < ee; i += 256) {
        unsigned v = (unsigned)ebuf[i];
        int slot = atomicAdd(&s_h[v >> 24], 1);
        srcs[slot] = (int)(v & 0xFFFFFFu);
      }
      __syncthreads();
    }
    if (blk == 0 && t == 0) off[n] = E;
  } else {
    // ================= GEMM1 path (hs1 = bf16(x @ W1), unscaled) ==========
    int l = t & 63, wave = t >> 6;
    int rl = l & 15, g = l >> 4;
    int ntb = (n + 127) >> 7;
    for (int tb = blk - CB; tb < ntb; tb += GB) {
      int row0 = tb * 128 + wave * 32;

      const float* xp[2];
#pragma unroll
      for (int rt = 0; rt < 2; ++rt) {
        int r = row0 + rt * 16 + rl;
        int rc = r < n ? r : n - 1;  // clamp; masked at store
        xp[rt] = x + (size_t)rc * NF + g * 8;
      }
      const bf16x8* wp = (const bf16x8*)Wb + l;

      f32x4 acc[2];
#pragma unroll
      for (int rt = 0; rt < 2; ++rt)
#pragma unroll
        for (int j = 0; j < 4; ++j) acc[rt][j] = 0.f;

      float xA[2][8], xB[2][8];

#define LOADC(BUF, CBX) { int _b = (CBX) * 32;                       \
  _Pragma("unroll") for (int rt = 0; rt < 2; ++rt)                   \
  _Pragma("unroll") for (int i = 0; i < 8; ++i)                      \
    BUF[rt][i] = xp[rt][_b + i]; }

#define LOADCG(BUF, CBX) { int _b = (CBX) * 32;                      \
  _Pragma("unroll") for (int rt = 0; rt < 2; ++rt)                   \
  _Pragma("unroll") for (int i = 0; i < 8; ++i)                      \
    BUF[rt][i] = (_b + g * 8 + i < NF) ? xp[rt][_b + i] : 0.f; }

#define DOC(BUF, CC) { bf16x8 _w = wp[(size_t)(CC) * 64];            \
  _Pragma("unroll") for (int rt = 0; rt < 2; ++rt) { bf16x8 _a;      \
    _Pragma("unroll") for (int i = 0; i < 8; ++i)                    \
      _a[i] = (short)f2bf(BUF[rt][i]);                               \
    acc[rt] = __builtin_amdgcn_mfma_f32_16x16x32_bf16(_a, _w, acc[rt], 0, 0, 0); } }

      LOADC(xA, 0);
      LOADC(xB, 1);
      int c = 0;
      for (; c + 4 < NCH; c += 2) {
        DOC(xA, c);     LOADC(xA, c + 2);
        DOC(xB, c + 1); LOADC(xB, c + 3);
      }
      DOC(xA, c);     LOADCG(xA, c + 2);
      DOC(xB, c + 1);
      DOC(xA, c + 2);
#undef LOADC
#undef LOADCG
#undef DOC

      // D layout (m89): col = lane&15, row_in_tile = (lane>>4)*4 + reg
#pragma unroll
      for (int rt = 0; rt < 2; ++rt)
#pragma unroll
        for (int r = 0; r < 4; ++r) {
          int row = row0 + rt * 16 + g * 4 + r;
          if (row < n) hs1[(size_t)row * NH + rl] = f2bf(acc[rt][r]);
        }
    }
  }
}

// ---------------- pull1 + bias + relu + GEMM2 fused (16 lanes/node) --------
// hs1 unscaled: acc = sum_s dis[s]*h1[s] + dis[d]*h1[d]; v = relu(dis[d]*acc+b1)
__global__ __launch_bounds__(256) void k_pull1(
    const int* __restrict__ off, const int* __restrict__ srcs,
    const float* __restrict__ dis, const uint4* __restrict__ hs1,
    const float* __restrict__ b1, const float* __restrict__ W2,
    uint4* __restrict__ hs2, int n) {
  int t = blockIdx.x * blockDim.x + threadIdx.x;
  int d = t >> 4;
  if (d >= n) return;
  int sub = t & 15, half = sub & 1, ph = sub >> 1;  // ph in [0,8)
  float dd = dis[d];

  float a[8] = {0.f, 0.f, 0.f, 0.f, 0.f, 0.f, 0.f, 0.f};
  if (ph == 0) acc8f(a, hs1[(size_t)d * 2 + half], dd);  // self loop

  int k = off[d] + ph, k1 = off[d + 1];
  for (; k + 8 < k1; k += 16) {  // 2 independent gathers in flight
    int s0 = srcs[k], s1 = srcs[k + 8];
    float c0 = dis[s0], c1 = dis[s1];
    uint4 r0 = hs1[(size_t)s0 * 2 + half];
    uint4 r1 = hs1[(size_t)s1 * 2 + half];
    acc8f(a, r0, c0);
    acc8f(a, r1, c1);
  }
  if (k < k1) {
    int s = srcs[k];
    acc8f(a, hs1[(size_t)s * 2 + half], dis[s]);
  }

#pragma unroll
  for (int i = 0; i < 8; ++i) {  // reduce over the 8 phases (lane bits 1..3)
    a[i] += __shfl_xor(a[i], 2);
    a[i] += __shfl_xor(a[i], 4);
    a[i] += __shfl_xor(a[i], 8);
  }

  float v[8];
#pragma unroll
  for (int i = 0; i < 8; ++i) v[i] = fmaxf(a[i] * dd + b1[half * 8 + i], 0.f);
  float p[NC];
#pragma unroll
  for (int c = 0; c < NC; ++c) {
    float s = 0.f;
#pragma unroll
    for (int i = 0; i < 8; ++i) s = fmaf(v[i], W2[(half * 8 + i) * NC + c], s);
    p[c] = s;
  }
#pragma unroll
  for (int c = 0; c < NC; ++c) p[c] += __shfl_xor(p[c], 1);  // combine halves
  if (sub == 0) {
    uint4 o;
    o.x = packbf(p[0] * dd, p[1] * dd);
    o.y = packbf(p[2] * dd, p[3] * dd);
    o.z = packbf(p[4] * dd, p[5] * dd);
    o.w = packbf(p[6] * dd, 0.f);  // pad col
    hs2[d] = o;
  }
}

// ---------------- pull2 + bias + relu + log_softmax (8 lanes/node) ---------
__global__ __launch_bounds__(256) void k_pull2(
    const int* __restrict__ off, const int* __restrict__ srcs,
    const float* __restrict__ dis, const uint4* __restrict__ hs2,
    const float* __restrict__ b2, float* __restrict__ out, int n) {
  int t = blockIdx.x * blockDim.x + threadIdx.x;
  int d = t >> 3;
  if (d >= n) return;
  int ph = t & 7;

  float a[8] = {0.f, 0.f, 0.f, 0.f, 0.f, 0.f, 0.f, 0.f};
  if (ph == 0) acc8(a, hs2[d]);  // self loop (hs2 pre-scaled)

  int k = off[d] + ph, k1 = off[d + 1];
  for (; k + 8 < k1; k += 16) {
    int s0 = srcs[k], s1 = srcs[k + 8];
    uint4 r0 = hs2[s0];
    uint4 r1 = hs2[s1];
    acc8(a, r0);
    acc8(a, r1);
  }
  if (k < k1) acc8(a, hs2[srcs[k]]);

#pragma unroll
  for (int i = 0; i < 8; ++i) {
    a[i] += __shfl_xor(a[i], 1);
    a[i] += __shfl_xor(a[i], 2);
    a[i] += __shfl_xor(a[i], 4);
  }
  float dd = dis[d];
  float u[NC];
#pragma unroll
  for (int c = 0; c < NC; ++c) u[c] = fmaxf(a[c] * dd + b2[c], 0.f);
  float m = u[0];
#pragma unroll
  for (int c = 1; c < NC; ++c) m = fmaxf(m, u[c]);
  float sum = 0.f;
#pragma unroll
  for (int c = 0; c < NC; ++c) sum += expf(u[c] - m);
  float lg = logf(sum);
  if (ph < NC) out[(size_t)d * NC + ph] = u[ph] - m - lg;
}

extern "C" void kernel_launch(void* const* d_in, const int* in_sizes, int n_in,
                              void* d_out, int out_size, void* d_ws, size_t ws_size,
                              hipStream_t stream) {
  const float* x  = (const float*)d_in[0];
  const int*   ei = (const int*)d_in[1];
  const float* W1 = (const float*)d_in[2];
  const float* b1 = (const float*)d_in[3];
  const float* W2 = (const float*)d_in[4];
  const float* b2 = (const float*)d_in[5];
  int n = in_sizes[0] / NF;   // 100000
  int E = in_sizes[1] / 2;    // 3200000
  int nbkt = (n + 255) >> 8;  // 391

  // workspace layout (16B-aligned regions)
  char* w = (char*)d_ws;
#define TAKE(ptrty, name, bytes) \
  ptrty name = (ptrty)w; w += ((size_t)(bytes) + 15) & ~(size_t)15;
  TAKE(unsigned short*, hs1,  sizeof(short) * (size_t)n * NH)
  TAKE(uint4*,          hs2,  16 * (size_t)n)
  TAKE(float*,          dis,  sizeof(float) * n)
  TAKE(short*,          Wb,   sizeof(short) * NCH * 64 * 8)
  TAKE(int*,            bcnt, sizeof(int) * 16 * NBKT_MAX)
  TAKE(int*,            bres, sizeof(int) * 16 * NBKT_MAX)
  TAKE(int*,            bar,  sizeof(int) * 16)
  TAKE(int*,            ebuf, sizeof(int) * (size_t)E)
  TAKE(int*,            off,  sizeof(int) * (n + 1))
  TAKE(int*,            srcs, sizeof(int) * (size_t)E)
#undef TAKE
  float* out = (float*)d_out;

  // prep: pack W fragments, zero counters/cursors/barrier
  k_prep<<<(NCH * 64 * 8 + 255) / 256, 256, 0, stream>>>(W1, Wb, bcnt, bres, bar);

  // fused CSR || GEMM1 (grid sized to guaranteed co-residency: 4 blocks/CU)
  k_fused<<<CB + GB, 256, 0, stream>>>(x, Wb, ei, bcnt, bres, bar, ebuf, off,
                                       srcs, dis, hs1, n, E, nbkt);

  k_pull1<<<((size_t)n * 16 + 255) / 256, 256, 0, stream>>>(
      off, srcs, dis, (const uint4*)hs1, b1, W2, hs2, n);
  k_pull2<<<((size_t)n * 8 + 255) / 256, 256, 0, stream>>>(
      off, srcs, dis, hs2, b2, out, n);
}